// Round 5
// baseline (37756.912 us; speedup 1.0000x reference)
//
#include <hip/hip_runtime.h>
#include <math.h>

#define VOCAB 32000
#define EMBD  512
#define HID   1024
#define BATCH 32
#define SEQ   64
#define TENC  64
#define NSTEP 63
#define G4    4096
#define NBLK  512          // persistent-kernel grid: 2 blocks/CU exact fit

__device__ __forceinline__ float4 ld4(const float* p) {
  return *reinterpret_cast<const float4*>(p);
}

struct LP {
  const int* tgt; const float* emb;
  const float* Wih0; const float* Whh0; const float* Wih1; const float* Whh1;
  const float* Wa; const float* Wc;
  const float* va; const float* bc;
  const float* bsum0; const float* bsum1;
  const float* PreAC; const float* zbuf;
  float* Pg; float* Pq; float* scores;
  float* h0; float* c0; float* h1; float* c1;
  float* AH;
  unsigned* bar;     // [0]=count [1]=generation
};

// ---- device-scope grid barrier (all NBLK blocks resident by construction) ----
__device__ __forceinline__ void gsync(unsigned* bar) {
  __syncthreads();
  if (threadIdx.x == 0) {
    __threadfence();   // agent-scope release of this block's writes
    unsigned g = __hip_atomic_load(&bar[1], __ATOMIC_RELAXED, __HIP_MEMORY_SCOPE_AGENT);
    unsigned old = __hip_atomic_fetch_add(&bar[0], 1u, __ATOMIC_ACQ_REL, __HIP_MEMORY_SCOPE_AGENT);
    if (old == NBLK - 1u) {
      __hip_atomic_store(&bar[0], 0u, __ATOMIC_RELAXED, __HIP_MEMORY_SCOPE_AGENT);
      __hip_atomic_store(&bar[1], g + 1u, __ATOMIC_RELEASE, __HIP_MEMORY_SCOPE_AGENT);
    } else {
      while (__hip_atomic_load(&bar[1], __ATOMIC_ACQUIRE, __HIP_MEMORY_SCOPE_AGENT) == g)
        __builtin_amdgcn_s_sleep(1);
    }
  }
  __syncthreads();
}

// ---- A/W element loaders for the three per-step GEMMs ----
template<int MODE>
__device__ __forceinline__ float4 ldA(const LP& P, int lr, int k, int t) {
  if (MODE == 0) {
    if (k < EMBD) {
      const int tok = P.tgt[lr * SEQ + t];
      return ld4(P.emb + (size_t)tok * EMBD + k);
    }
    if (k < EMBD + HID) {
      const float* ah = t ? (P.AH + (size_t)(t-1) * BATCH * HID) : P.zbuf;
      return ld4(ah + lr * HID + (k - EMBD));
    }
    return ld4(P.h0 + lr * HID + (k - EMBD - HID));
  } else if (MODE == 1) {
    if (k < HID) return ld4(P.h0 + lr * HID + k);
    return ld4(P.h1 + lr * HID + (k - HID));
  } else {
    return ld4(P.h1 + lr * HID + k);
  }
}

template<int MODE>
__device__ __forceinline__ float4 ldW(const LP& P, int n, int k) {
  if (MODE == 0) {
    if (k < EMBD + HID) return ld4(P.Wih0 + (size_t)n * (EMBD + HID) + k);
    return ld4(P.Whh0 + (size_t)n * HID + (k - EMBD - HID));
  } else if (MODE == 1) {
    if (k < HID) return ld4(P.Wih1 + (size_t)n * HID + k);
    return ld4(P.Whh1 + (size_t)n * HID + (k - HID));
  } else {
    if (n < HID) return ld4(P.Wa + (size_t)n * (2*HID) + k);
    return ld4(P.Wc + (size_t)(n - HID) * (2*HID) + k);
  }
}

// partial GEMM: dst[sp][32][N] = A[32 x (kbeg..kend)] * W[n0..n0+31][..]^T
// 2x2 per thread, register double-buffered global->LDS staging.
template<int MODE>
__device__ void gpart(const LP& P, float* At, float* Wt,
                      int n0, int sp, int kbeg, int kend, int t,
                      float* dst, int N) {
  const int tid = threadIdx.x;
  const int lr = tid >> 3, lc = (tid & 7) << 2;
  const int tn = tid & 15, tm = tid >> 4;
  float a00=0.f, a01=0.f, a10=0.f, a11=0.f;
  float4 av = ldA<MODE>(P, lr, kbeg + lc, t);
  float4 wv = ldW<MODE>(P, n0 + lr, kbeg + lc);
  for (int k0 = kbeg; k0 < kend; k0 += 32) {
    float4 avn, wvn;
    const bool more = (k0 + 32) < kend;
    if (more) {
      avn = ldA<MODE>(P, lr, k0 + 32 + lc, t);
      wvn = ldW<MODE>(P, n0 + lr, k0 + 32 + lc);
    }
    __syncthreads();
    At[(lc+0)*34+lr]=av.x; At[(lc+1)*34+lr]=av.y; At[(lc+2)*34+lr]=av.z; At[(lc+3)*34+lr]=av.w;
    Wt[(lc+0)*34+lr]=wv.x; Wt[(lc+1)*34+lr]=wv.y; Wt[(lc+2)*34+lr]=wv.z; Wt[(lc+3)*34+lr]=wv.w;
    __syncthreads();
    #pragma unroll
    for (int kk = 0; kk < 32; ++kk) {
      const float2 a = *reinterpret_cast<const float2*>(&At[kk*34 + tm*2]);
      const float2 w = *reinterpret_cast<const float2*>(&Wt[kk*34 + tn*2]);
      a00 += a.x*w.x; a01 += a.x*w.y; a10 += a.y*w.x; a11 += a.y*w.y;
    }
    av = avn; wv = wvn;
  }
  const int na = n0 + tn*2, ma = tm*2;
  dst[((size_t)sp*BATCH + ma  )*N + na  ] = a00;
  dst[((size_t)sp*BATCH + ma  )*N + na+1] = a01;
  dst[((size_t)sp*BATCH + ma+1)*N + na  ] = a10;
  dst[((size_t)sp*BATCH + ma+1)*N + na+1] = a11;
}

__device__ __forceinline__ void cell_phase(const float* Pg, const float* bsum,
                                           float* h, float* c, int bid, int tid) {
  if (tid < 64) {
    const int i = bid*64 + tid;
    const int b = i >> 10, n = i & (HID-1);
    float g[4];
    #pragma unroll
    for (int gi = 0; gi < 4; ++gi) {
      const int col = gi*HID + n;
      float s = bsum[col];
      #pragma unroll
      for (int sp = 0; sp < 4; ++sp) s += Pg[((size_t)sp*BATCH + b)*G4 + col];
      g[gi] = s;
    }
    const float si = 1.f/(1.f+expf(-g[0]));
    const float sf = 1.f/(1.f+expf(-g[1]));
    const float so = 1.f/(1.f+expf(-g[3]));
    const float cn = sf*c[i] + si*tanhf(g[2]);
    c[i] = cn;
    h[i] = so*tanhf(cn);
  }
}

// ---- the persistent 63-step recurrence kernel ----
__global__ __launch_bounds__(256, 2) void loop_k(LP P) {
  __shared__ float SH[2*32*34 + 64];   // gemm tiles / F1 QS+red / F2 buffers
  float* At = SH;
  float* Wt = SH + 32*34;
  const int bid = blockIdx.x;
  const int tid = threadIdx.x;

  for (int t = 0; t < NSTEP; ++t) {
    { // A: gates0 partials, K=2560, 128 n-tiles x 4 K-splits(640)
      const int nt = bid >> 2, sp = bid & 3;
      gpart<0>(P, At, Wt, nt*32, sp, sp*640, sp*640+640, t, P.Pg, G4);
    }
    gsync(P.bar);
    cell_phase(P.Pg, P.bsum0, P.h0, P.c0, bid, tid);   // B: cell0
    gsync(P.bar);
    { // C: gates1 partials, K=2048, 128 x 4(512)
      const int nt = bid >> 2, sp = bid & 3;
      gpart<1>(P, At, Wt, nt*32, sp, sp*512, sp*512+512, t, P.Pg, G4);
    }
    gsync(P.bar);
    cell_phase(P.Pg, P.bsum1, P.h1, P.c1, bid, tid);   // D: cell1
    gsync(P.bar);
    if (bid < 256) { // E: proj [q | Wc1*h1] partials, K=1024, 64 x 4(256)
      const int nt = bid >> 2, sp = bid & 3;
      gpart<2>(P, At, Wt, nt*32, sp, sp*256, sp*256+256, t, P.Pq, 2*HID);
    }
    gsync(P.bar);
    { // F1: scores. 512 blocks = 32 b x 16 te-groups(4)
      const int b = bid >> 4, teg = bid & 15;
      float* QS  = SH;          // [1024]
      float* red = SH + 1024;   // [16]
      for (int idx = tid; idx < HID; idx += 256) {
        float s = 0.f;
        #pragma unroll
        for (int sp = 0; sp < 4; ++sp) s += P.Pq[((size_t)sp*BATCH + b)*2048 + idx];
        QS[idx] = s;
      }
      __syncthreads();
      const int lane = tid & 63, wid = tid >> 6;
      #pragma unroll
      for (int j = 0; j < 4; ++j) {
        const int te = teg*4 + j;
        const float* pr = P.PreAC + ((size_t)te*BATCH + b)*2048;
        float s = 0.f;
        for (int idx = tid; idx < HID; idx += 256)
          s += P.va[idx] * tanhf(QS[idx] + pr[idx]);
        #pragma unroll
        for (int off = 32; off; off >>= 1) s += __shfl_xor(s, off);
        if (lane == 0) red[j*4 + wid] = s;
      }
      __syncthreads();
      if (tid < 4)
        P.scores[b*TENC + teg*4 + tid] =
          red[tid*4+0] + red[tid*4+1] + red[tid*4+2] + red[tid*4+3];
    }
    gsync(P.bar);
    { // F2: softmax + context + attn_h -> AH[t]. 512 = 32 b x 16 h-chunks(64)
      const int b = bid >> 4, hc0 = (bid & 15) * 64;
      float* CTX = SH + 1024;   // [4][64]
      float* SC  = SH + 1280;   // [64]
      float* W64 = SH + 1344;   // [64]
      if (tid < TENC) SC[tid] = P.scores[b*TENC + tid];
      __syncthreads();
      if (tid < 64) {
        const float v = SC[tid];
        float mx = v;
        #pragma unroll
        for (int off = 32; off; off >>= 1) mx = fmaxf(mx, __shfl_xor(mx, off));
        const float e = expf(v - mx);
        float sum = e;
        #pragma unroll
        for (int off = 32; off; off >>= 1) sum += __shfl_xor(sum, off);
        W64[tid] = e / sum;
      }
      __syncthreads();
      const int lane = tid & 63, wid = tid >> 6;
      const int h = hc0 + lane;
      float acc = 0.f;
      #pragma unroll
      for (int j = 0; j < 16; ++j) {
        const int te = wid*16 + j;
        acc += W64[te] * P.PreAC[((size_t)te*BATCH + b)*2048 + HID + h];
      }
      CTX[wid*64 + lane] = acc;
      __syncthreads();
      if (tid < 64) {
        const int hh = hc0 + tid;
        float ctx = CTX[tid] + CTX[64+tid] + CTX[128+tid] + CTX[192+tid];
        float hcs = P.bc[hh];
        #pragma unroll
        for (int sp = 0; sp < 4; ++sp)
          hcs += P.Pq[((size_t)sp*BATCH + b)*2048 + HID + hh];
        P.AH[((size_t)t*BATCH + b)*HID + hh] = tanhf(ctx + hcs);
      }
    }
    gsync(P.bar);
  }
}

// ---- wide GEMM, 32m x 256n tiles, 4x8/thread, K=1024 ----
// WM 0: logits C[2016 x 32000] = AH*Wo^T + bo     (A stride 1024)
// WM 1: PreAC  C[2048 x 2048]  = enc*[Wa2;Wc2]^T + [ba;0]
struct WGP {
  const float* A; const float* W; const float* W2; const float* bias;
  float* C; int ldc;
};

template<int WM>
__device__ __forceinline__ float4 ldWL(const WGP& P, int r, int k) {
  if (WM == 0) return ld4(P.W + (size_t)r * 1024 + k);
  if (r < HID) return ld4(P.W  + (size_t)r * (2*HID) + HID + k);
  return ld4(P.W2 + (size_t)(r - HID) * (2*HID) + HID + k);
}

template<int WM>
__global__ __launch_bounds__(256, 2) void gemmL(WGP P) {
  __shared__ float At[32*36];
  __shared__ float Wt[32*260];
  const int tid = threadIdx.x;
  const int m0 = blockIdx.x * 32;       // m fastest: blocks sharing W-panel co-run
  const int n0 = blockIdx.y * 256;
  const int lr = tid >> 3, lc = (tid & 7) << 2;
  const int tn = tid & 31, tm = tid >> 5;
  float acc[4][8];
  #pragma unroll
  for (int i = 0; i < 4; ++i)
    #pragma unroll
    for (int x = 0; x < 8; ++x) acc[i][x] = 0.f;

  float4 av = ld4(P.A + (size_t)(m0+lr)*1024 + lc);
  float4 wv[8];
  #pragma unroll
  for (int it = 0; it < 8; ++it) wv[it] = ldWL<WM>(P, n0 + lr + it*32, lc);

  for (int k0 = 0; k0 < 1024; k0 += 32) {
    float4 avn, wvn[8];
    const bool more = k0 + 32 < 1024;
    if (more) {
      avn = ld4(P.A + (size_t)(m0+lr)*1024 + k0 + 32 + lc);
      #pragma unroll
      for (int it = 0; it < 8; ++it) wvn[it] = ldWL<WM>(P, n0 + lr + it*32, k0 + 32 + lc);
    }
    __syncthreads();
    At[(lc+0)*36+lr]=av.x; At[(lc+1)*36+lr]=av.y; At[(lc+2)*36+lr]=av.z; At[(lc+3)*36+lr]=av.w;
    #pragma unroll
    for (int it = 0; it < 8; ++it) {
      const int r = lr + it*32;
      Wt[(lc+0)*260+r]=wv[it].x; Wt[(lc+1)*260+r]=wv[it].y;
      Wt[(lc+2)*260+r]=wv[it].z; Wt[(lc+3)*260+r]=wv[it].w;
    }
    __syncthreads();
    #pragma unroll
    for (int kk = 0; kk < 32; ++kk) {
      const float4 a  = *reinterpret_cast<const float4*>(&At[kk*36 + tm*4]);
      const float4 w0 = *reinterpret_cast<const float4*>(&Wt[kk*260 + tn*8]);
      const float4 w1 = *reinterpret_cast<const float4*>(&Wt[kk*260 + tn*8 + 4]);
      #pragma unroll
      for (int i = 0; i < 4; ++i) {
        const float ai = (&a.x)[i];
        acc[i][0]+=ai*w0.x; acc[i][1]+=ai*w0.y; acc[i][2]+=ai*w0.z; acc[i][3]+=ai*w0.w;
        acc[i][4]+=ai*w1.x; acc[i][5]+=ai*w1.y; acc[i][6]+=ai*w1.z; acc[i][7]+=ai*w1.w;
      }
    }
    av = avn;
    #pragma unroll
    for (int it = 0; it < 8; ++it) wv[it] = wvn[it];
  }
  const int na = n0 + tn*8, ma = m0 + tm*4;
  float bb[8];
  #pragma unroll
  for (int x = 0; x < 8; ++x) {
    if (WM == 0) bb[x] = P.bias[na+x];
    else         bb[x] = (na + x < HID) ? P.bias[na+x] : 0.f;
  }
  #pragma unroll
  for (int i = 0; i < 4; ++i)
    #pragma unroll
    for (int x = 0; x < 8; ++x)
      P.C[(size_t)(ma+i)*P.ldc + na + x] = acc[i][x] + bb[x];
}

// per-(b,t): logits row -> log-softmax in place + argmax word
__global__ __launch_bounds__(256) void lsm_k(float* __restrict__ out,
                                             float* __restrict__ words) {
  const int b = blockIdx.x;
  const int t = blockIdx.y;
  float* row = out + ((size_t)t*BATCH + b)*VOCAB;
  const int tid = threadIdx.x;
  float m = -INFINITY; int mi = 0;
  for (int v = tid; v < VOCAB; v += 256) {
    const float x = row[v];
    if (x > m) { m = x; mi = v; }
  }
  __shared__ float sm[256]; __shared__ int si[256];
  sm[tid] = m; si[tid] = mi;
  __syncthreads();
  for (int s2 = 128; s2; s2 >>= 1) {
    if (tid < s2) {
      const float om = sm[tid+s2]; const int oi = si[tid+s2];
      if (om > sm[tid] || (om == sm[tid] && oi < si[tid])) { sm[tid]=om; si[tid]=oi; }
    }
    __syncthreads();
  }
  const float mx = sm[0]; const int amax = si[0];
  float s = 0.f;
  for (int v = tid; v < VOCAB; v += 256) s += expf(row[v]-mx);
  __shared__ float ss[256];
  ss[tid] = s; __syncthreads();
  for (int s2=128; s2; s2>>=1) { if (tid < s2) ss[tid] += ss[tid+s2]; __syncthreads(); }
  const float lse = logf(ss[0]) + mx;
  for (int v = tid; v < VOCAB; v += 256) row[v] = row[v] - lse;
  if (tid == 0) words[(size_t)t*BATCH + b] = (float)amax;
}

__global__ __launch_bounds__(256) void init_k(const float* __restrict__ enc_h,
                                              const float* __restrict__ enc_c,
                                              const float* __restrict__ bih0,
                                              const float* __restrict__ bhh0,
                                              const float* __restrict__ bih1,
                                              const float* __restrict__ bhh1,
                                              float* h0, float* h1, float* c0,
                                              float* c1, float* zbuf,
                                              float* bsum0, float* bsum1,
                                              unsigned* bar) {
  const int i = blockIdx.x*256 + threadIdx.x;
  if (i < BATCH*HID) {
    h0[i] = enc_h[i]; h1[i] = enc_h[BATCH*HID + i];
    c0[i] = enc_c[i]; c1[i] = enc_c[BATCH*HID + i];
    zbuf[i] = 0.f;
  }
  if (i < G4) {
    bsum0[i] = bih0[i] + bhh0[i];
    bsum1[i] = bih1[i] + bhh1[i];
  }
  if (i < 2) bar[i] = 0u;
}

extern "C" void kernel_launch(void* const* d_in, const int* in_sizes, int n_in,
                              void* d_out, int out_size, void* d_ws, size_t ws_size,
                              hipStream_t stream) {
  const int*   tgt   = (const int*)d_in[0];
  const float* enc_h = (const float*)d_in[1];
  const float* enc_c = (const float*)d_in[2];
  const float* enc   = (const float*)d_in[3];
  const float* emb   = (const float*)d_in[4];
  const float* Wih0  = (const float*)d_in[5];
  const float* Whh0  = (const float*)d_in[6];
  const float* bih0  = (const float*)d_in[7];
  const float* bhh0  = (const float*)d_in[8];
  const float* Wih1  = (const float*)d_in[9];
  const float* Whh1  = (const float*)d_in[10];
  const float* bih1  = (const float*)d_in[11];
  const float* bhh1  = (const float*)d_in[12];
  const float* Wa    = (const float*)d_in[13];
  const float* ba    = (const float*)d_in[14];
  const float* va    = (const float*)d_in[15];
  const float* Wc    = (const float*)d_in[16];
  const float* bc    = (const float*)d_in[17];
  const float* Wo    = (const float*)d_in[18];
  const float* bo    = (const float*)d_in[19];

  float* ws    = (float*)d_ws;
  float* PreAC = ws;                                    // [2048,2048]
  float* AH    = PreAC + (size_t)2048*2048;             // [63,32,1024]
  float* Pg    = AH    + (size_t)NSTEP*BATCH*HID;       // [4,32,4096]
  float* Pq    = Pg    + (size_t)4*BATCH*G4;            // [4,32,2048]
  float* h0    = Pq    + (size_t)4*BATCH*2048;
  float* c0    = h0  + BATCH*HID;
  float* h1v   = c0  + BATCH*HID;
  float* c1v   = h1v + BATCH*HID;
  float* zbuf  = c1v + BATCH*HID;
  float* bsum0 = zbuf + BATCH*HID;
  float* bsum1 = bsum0 + G4;
  float* scores= bsum1 + G4;                            // [32,64]
  unsigned* bar = (unsigned*)(scores + BATCH*TENC);

  float* out   = (float*)d_out;
  float* words = out + (size_t)NSTEP*BATCH*VOCAB;

  init_k<<<dim3(128), 256, 0, stream>>>(enc_h, enc_c, bih0, bhh0, bih1, bhh1,
                                        h0, h1v, c0, c1v, zbuf, bsum0, bsum1, bar);

  { // PreAC = enc @ [Wa2; Wc2]^T + [ba; 0]
    WGP p; p.A = enc; p.W = Wa; p.W2 = Wc; p.bias = ba; p.C = PreAC; p.ldc = 2048;
    gemmL<1><<<dim3(64, 8), 256, 0, stream>>>(p);
  }

  { // persistent 63-step recurrence
    LP p;
    p.tgt = tgt; p.emb = emb;
    p.Wih0 = Wih0; p.Whh0 = Whh0; p.Wih1 = Wih1; p.Whh1 = Whh1;
    p.Wa = Wa; p.Wc = Wc; p.va = va; p.bc = bc;
    p.bsum0 = bsum0; p.bsum1 = bsum1;
    p.PreAC = PreAC; p.zbuf = zbuf;
    p.Pg = Pg; p.Pq = Pq; p.scores = scores;
    p.h0 = h0; p.c0 = c0; p.h1 = h1v; p.c1 = c1v;
    p.AH = AH; p.bar = bar;
    loop_k<<<dim3(NBLK), 256, 0, stream>>>(p);
  }

  { // batched logits over all steps: [2016 x 32000], K=1024
    WGP p; p.A = AH; p.W = Wo; p.W2 = nullptr; p.bias = bo; p.C = out; p.ldc = VOCAB;
    gemmL<0><<<dim3(NSTEP*BATCH/32, VOCAB/256), 256, 0, stream>>>(p);
  }
  lsm_k<<<dim3(BATCH, NSTEP), 256, 0, stream>>>(out, words);
}

// Round 6
// 17682.939 us; speedup vs baseline: 2.1352x; 2.1352x over previous
//
#include <hip/hip_runtime.h>
#include <math.h>

#define VOCAB 32000
#define EMBD  512
#define HID   1024
#define BATCH 32
#define SEQ   64
#define TENC  64
#define NSTEP 63
#define G4    4096
#define NSP   8            // K-splits for the per-step GEMMs

__device__ __forceinline__ float4 ld4(const float* p) {
  return *reinterpret_cast<const float4*>(p);
}

// ============ fused gates GEMM + (last block) LSTM cell ============
// MODE 0: A=[emb(tok)|ah_prev|h0_in] K=2560 chunk 320, W=[Wih0|Whh0]
// MODE 1: A=[h0_new|h1_in]           K=2048 chunk 256, W=[Wih1|Whh1]
// grid (32 nt, 8 sp). Block (nt,sp) computes partial[sp][32b][4 gates x 32cols].
// Last-arriving sp-block for nt reduces all 8 partials + bias -> cell update.
struct GK {
  const int* tgt; const float* emb;
  const float* segA; const float* segB;     // M0: ah_prev,h0_in ; M1: h0_new,h1_in
  const float* WA; const float* WB;
  const float* bsum;
  float* Pg;
  float* h_out; float* c;                   // cell outputs (h_out ping-pong, c in-place)
  unsigned* cnt;                            // [32] monotonic arrival counters
  int t;
};

template<int MODE>
__device__ __forceinline__ float4 gldA(const GK& P, int lr, int k) {
  if (MODE == 0) {
    if (k < EMBD) {
      const int tok = P.tgt[lr * SEQ + P.t];
      return ld4(P.emb + (size_t)tok * EMBD + k);
    }
    if (k < EMBD + HID) return ld4(P.segA + lr * HID + (k - EMBD));
    return ld4(P.segB + lr * HID + (k - EMBD - HID));
  } else {
    if (k < HID) return ld4(P.segA + lr * HID + k);
    return ld4(P.segB + lr * HID + (k - HID));
  }
}

template<int MODE>
__device__ __forceinline__ float4 gldW(const GK& P, int row, int k) {
  if (MODE == 0) {
    if (k < EMBD + HID) return ld4(P.WA + (size_t)row * (EMBD + HID) + k);
    return ld4(P.WB + (size_t)row * HID + (k - EMBD - HID));
  } else {
    if (k < HID) return ld4(P.WA + (size_t)row * HID + k);
    return ld4(P.WB + (size_t)row * HID + (k - HID));
  }
}

template<int MODE>
__global__ __launch_bounds__(256) void gates_k(GK P) {
  __shared__ float At[32*34];
  __shared__ float Wt[4][32*34];
  __shared__ unsigned lastv;
  const int nt = blockIdx.x;          // 0..31 : 32 columns of each of the 4 gates
  const int sp = blockIdx.y;          // 0..7  : K split
  const int tid = threadIdx.x;
  const int lr = tid >> 3, lc = (tid & 7) << 2;
  const int tn = tid & 15, tm = tid >> 4;
  const int CH = (MODE == 0) ? 320 : 256;
  const int kbeg = sp * CH;

  float acc[4][2][2];
  #pragma unroll
  for (int g = 0; g < 4; ++g) {
    acc[g][0][0]=0.f; acc[g][0][1]=0.f; acc[g][1][0]=0.f; acc[g][1][1]=0.f;
  }

  float4 av = gldA<MODE>(P, lr, kbeg + lc);
  float4 wv[4], avn, wvn[4];
  #pragma unroll
  for (int g = 0; g < 4; ++g) wv[g] = gldW<MODE>(P, g*1024 + nt*32 + lr, kbeg + lc);

  for (int k0 = kbeg; k0 < kbeg + CH; k0 += 32) {
    const bool more = (k0 + 32) < kbeg + CH;
    if (more) {
      avn = gldA<MODE>(P, lr, k0 + 32 + lc);
      #pragma unroll
      for (int g = 0; g < 4; ++g) wvn[g] = gldW<MODE>(P, g*1024 + nt*32 + lr, k0 + 32 + lc);
    }
    __syncthreads();
    At[(lc+0)*34+lr]=av.x; At[(lc+1)*34+lr]=av.y; At[(lc+2)*34+lr]=av.z; At[(lc+3)*34+lr]=av.w;
    #pragma unroll
    for (int g = 0; g < 4; ++g) {
      Wt[g][(lc+0)*34+lr]=wv[g].x; Wt[g][(lc+1)*34+lr]=wv[g].y;
      Wt[g][(lc+2)*34+lr]=wv[g].z; Wt[g][(lc+3)*34+lr]=wv[g].w;
    }
    __syncthreads();
    #pragma unroll
    for (int kk = 0; kk < 32; ++kk) {
      const float2 a = *reinterpret_cast<const float2*>(&At[kk*34 + tm*2]);
      #pragma unroll
      for (int g = 0; g < 4; ++g) {
        const float2 w = *reinterpret_cast<const float2*>(&Wt[g][kk*34 + tn*2]);
        acc[g][0][0] += a.x*w.x; acc[g][0][1] += a.x*w.y;
        acc[g][1][0] += a.y*w.x; acc[g][1][1] += a.y*w.y;
      }
    }
    av = avn;
    #pragma unroll
    for (int g = 0; g < 4; ++g) wv[g] = wvn[g];
  }

  { // write partials: Pg[sp][b][g*1024 + nt*32 + col]
    const int na = nt*32 + tn*2, ma = tm*2;
    float* dst = P.Pg + (size_t)sp * BATCH * G4;
    #pragma unroll
    for (int g = 0; g < 4; ++g) {
      dst[(size_t)(ma  )*G4 + g*1024 + na  ] = acc[g][0][0];
      dst[(size_t)(ma  )*G4 + g*1024 + na+1] = acc[g][0][1];
      dst[(size_t)(ma+1)*G4 + g*1024 + na  ] = acc[g][1][0];
      dst[(size_t)(ma+1)*G4 + g*1024 + na+1] = acc[g][1][1];
    }
  }
  __threadfence();                                   // release partials (device scope)
  if (tid == 0) {
    const unsigned old = __hip_atomic_fetch_add(&P.cnt[nt], 1u,
                           __ATOMIC_ACQ_REL, __HIP_MEMORY_SCOPE_AGENT);
    lastv = ((old & (NSP-1)) == NSP-1) ? 1u : 0u;    // counters are monotonic across steps
  }
  __syncthreads();
  if (!lastv) return;
  __threadfence();                                   // acquire all splits' partials

  // cell update for columns nt*32 .. nt*32+31, all 32 batches (1024 elems)
  #pragma unroll
  for (int q = 0; q < 4; ++q) {
    const int idx = q*256 + tid;
    const int b = idx >> 5, n = nt*32 + (idx & 31);
    float g4[4];
    #pragma unroll
    for (int gi = 0; gi < 4; ++gi) {
      const int col = gi*1024 + n;
      float s = P.bsum[col];
      #pragma unroll
      for (int s8 = 0; s8 < NSP; ++s8) s += P.Pg[((size_t)s8*BATCH + b)*G4 + col];
      g4[gi] = s;
    }
    const float si = 1.f/(1.f+expf(-g4[0]));
    const float sf = 1.f/(1.f+expf(-g4[1]));
    const float so = 1.f/(1.f+expf(-g4[3]));
    const int i = b*HID + n;
    const float cn = sf*P.c[i] + si*tanhf(g4[2]);
    P.c[i] = cn;
    P.h_out[i] = so*tanhf(cn);
  }
}

// ============ proj partials: Pq[sp][32][2048] = h1 x [Wa1; Wc1]^T ============
struct PK { const float* A; const float* Wa; const float* Wc; float* Pq; };

__global__ __launch_bounds__(256) void proj_k(PK P) {
  __shared__ float At[32*34];
  __shared__ float Wt[32*34];
  const int nt = blockIdx.x;          // 0..63
  const int sp = blockIdx.y;          // 0..7, chunk 128
  const int tid = threadIdx.x;
  const int lr = tid >> 3, lc = (tid & 7) << 2;
  const int tn = tid & 15, tm = tid >> 4;
  const int kbeg = sp * 128;
  const int row = nt*32 + lr;
  const float* wbase = (row < HID) ? (P.Wa + (size_t)row * (2*HID))
                                   : (P.Wc + (size_t)(row - HID) * (2*HID));
  float a00=0.f, a01=0.f, a10=0.f, a11=0.f;
  float4 av = ld4(P.A + lr*HID + kbeg + lc);
  float4 wv = ld4(wbase + kbeg + lc);
  for (int k0 = kbeg; k0 < kbeg + 128; k0 += 32) {
    const bool more = (k0 + 32) < kbeg + 128;
    float4 avn, wvn;
    if (more) {
      avn = ld4(P.A + lr*HID + k0 + 32 + lc);
      wvn = ld4(wbase + k0 + 32 + lc);
    }
    __syncthreads();
    At[(lc+0)*34+lr]=av.x; At[(lc+1)*34+lr]=av.y; At[(lc+2)*34+lr]=av.z; At[(lc+3)*34+lr]=av.w;
    Wt[(lc+0)*34+lr]=wv.x; Wt[(lc+1)*34+lr]=wv.y; Wt[(lc+2)*34+lr]=wv.z; Wt[(lc+3)*34+lr]=wv.w;
    __syncthreads();
    #pragma unroll
    for (int kk = 0; kk < 32; ++kk) {
      const float2 a = *reinterpret_cast<const float2*>(&At[kk*34 + tm*2]);
      const float2 w = *reinterpret_cast<const float2*>(&Wt[kk*34 + tn*2]);
      a00 += a.x*w.x; a01 += a.x*w.y; a10 += a.y*w.x; a11 += a.y*w.y;
    }
    av = avn; wv = wvn;
  }
  const int na = nt*32 + tn*2, ma = tm*2;
  P.Pq[((size_t)sp*BATCH + ma  )*2048 + na  ] = a00;
  P.Pq[((size_t)sp*BATCH + ma  )*2048 + na+1] = a01;
  P.Pq[((size_t)sp*BATCH + ma+1)*2048 + na  ] = a10;
  P.Pq[((size_t)sp*BATCH + ma+1)*2048 + na+1] = a11;
}

// ============ fused attention: q-sum, scores, softmax, context, attn_h ============
struct AK {
  const float* Pq; const float* PreAC; const float* va; const float* bc;
  float* AHt;
};

__global__ __launch_bounds__(256) void attn_k(AK P) {
  const int b = blockIdx.x, tid = threadIdx.x;
  const int lane = tid & 63, wid = tid >> 6;
  __shared__ float QS[HID];
  __shared__ float sw[TENC];
  __shared__ float W64[TENC];
  for (int idx = tid; idx < HID; idx += 256) {
    float s = 0.f;
    #pragma unroll
    for (int sp = 0; sp < NSP; ++sp) s += P.Pq[((size_t)sp*BATCH + b)*2048 + idx];
    QS[idx] = s;
  }
  __syncthreads();
  float vreg[16];
  #pragma unroll
  for (int i2 = 0; i2 < 16; ++i2) vreg[i2] = P.va[lane + 64*i2];
  #pragma unroll
  for (int j = 0; j < 16; ++j) {
    const int te = wid*16 + j;
    const float* pr = P.PreAC + ((size_t)te*BATCH + b)*2048;
    float s = 0.f;
    #pragma unroll
    for (int i2 = 0; i2 < 16; ++i2) {
      const int idx = lane + 64*i2;
      s += vreg[i2] * tanhf(QS[idx] + pr[idx]);
    }
    #pragma unroll
    for (int off = 32; off; off >>= 1) s += __shfl_xor(s, off);
    if (lane == 0) sw[te] = s;
  }
  __syncthreads();
  if (tid < TENC) {
    const float v = sw[tid];
    float mx = v;
    #pragma unroll
    for (int off = 32; off; off >>= 1) mx = fmaxf(mx, __shfl_xor(mx, off));
    const float e = expf(v - mx);
    float sum = e;
    #pragma unroll
    for (int off = 32; off; off >>= 1) sum += __shfl_xor(sum, off);
    W64[tid] = e / sum;
  }
  __syncthreads();
  #pragma unroll
  for (int q = 0; q < 4; ++q) {
    const int hh = q*256 + tid;
    float acc = 0.f;
    #pragma unroll 8
    for (int te = 0; te < TENC; ++te)
      acc += W64[te] * P.PreAC[((size_t)te*BATCH + b)*2048 + HID + hh];
    float hc = P.bc[hh];
    #pragma unroll
    for (int sp = 0; sp < NSP; ++sp) hc += P.Pq[((size_t)sp*BATCH + b)*2048 + HID + hh];
    P.AHt[(size_t)b*HID + hh] = tanhf(acc + hc);
  }
}

// ============ wide GEMM, 32m x 256n tiles, 4x8/thread, K=1024 ============
// WM 0: logits C[2016 x 32000] = AH*Wo^T + bo
// WM 1: PreAC  C[2048 x 2048]  = enc*[Wa2;Wc2]^T + [ba;0]
struct WGP {
  const float* A; const float* W; const float* W2; const float* bias;
  float* C; int ldc;
};

template<int WM>
__device__ __forceinline__ float4 ldWL(const WGP& P, int r, int k) {
  if (WM == 0) return ld4(P.W + (size_t)r * 1024 + k);
  if (r < HID) return ld4(P.W  + (size_t)r * (2*HID) + HID + k);
  return ld4(P.W2 + (size_t)(r - HID) * (2*HID) + HID + k);
}

template<int WM>
__global__ __launch_bounds__(256, 2) void gemmL(WGP P) {
  __shared__ float At[32*36];
  __shared__ float Wt[32*260];
  const int tid = threadIdx.x;
  const int m0 = blockIdx.x * 32;       // m fastest: blocks sharing W-panel co-run
  const int n0 = blockIdx.y * 256;
  const int lr = tid >> 3, lc = (tid & 7) << 2;
  const int tn = tid & 31, tm = tid >> 5;
  float acc[4][8];
  #pragma unroll
  for (int i = 0; i < 4; ++i)
    #pragma unroll
    for (int x = 0; x < 8; ++x) acc[i][x] = 0.f;

  float4 av = ld4(P.A + (size_t)(m0+lr)*1024 + lc);
  float4 wv[8];
  #pragma unroll
  for (int it = 0; it < 8; ++it) wv[it] = ldWL<WM>(P, n0 + lr + it*32, lc);

  for (int k0 = 0; k0 < 1024; k0 += 32) {
    float4 avn, wvn[8];
    const bool more = k0 + 32 < 1024;
    if (more) {
      avn = ld4(P.A + (size_t)(m0+lr)*1024 + k0 + 32 + lc);
      #pragma unroll
      for (int it = 0; it < 8; ++it) wvn[it] = ldWL<WM>(P, n0 + lr + it*32, k0 + 32 + lc);
    }
    __syncthreads();
    At[(lc+0)*36+lr]=av.x; At[(lc+1)*36+lr]=av.y; At[(lc+2)*36+lr]=av.z; At[(lc+3)*36+lr]=av.w;
    #pragma unroll
    for (int it = 0; it < 8; ++it) {
      const int r = lr + it*32;
      Wt[(lc+0)*260+r]=wv[it].x; Wt[(lc+1)*260+r]=wv[it].y;
      Wt[(lc+2)*260+r]=wv[it].z; Wt[(lc+3)*260+r]=wv[it].w;
    }
    __syncthreads();
    #pragma unroll
    for (int kk = 0; kk < 32; ++kk) {
      const float4 a  = *reinterpret_cast<const float4*>(&At[kk*36 + tm*4]);
      const float4 w0 = *reinterpret_cast<const float4*>(&Wt[kk*260 + tn*8]);
      const float4 w1 = *reinterpret_cast<const float4*>(&Wt[kk*260 + tn*8 + 4]);
      #pragma unroll
      for (int i = 0; i < 4; ++i) {
        const float ai = (&a.x)[i];
        acc[i][0]+=ai*w0.x; acc[i][1]+=ai*w0.y; acc[i][2]+=ai*w0.z; acc[i][3]+=ai*w0.w;
        acc[i][4]+=ai*w1.x; acc[i][5]+=ai*w1.y; acc[i][6]+=ai*w1.z; acc[i][7]+=ai*w1.w;
      }
    }
    av = avn;
    #pragma unroll
    for (int it = 0; it < 8; ++it) wv[it] = wvn[it];
  }
  const int na = n0 + tn*8, ma = m0 + tm*4;
  float bb[8];
  #pragma unroll
  for (int x = 0; x < 8; ++x) {
    if (WM == 0) bb[x] = P.bias[na+x];
    else         bb[x] = (na + x < HID) ? P.bias[na+x] : 0.f;
  }
  #pragma unroll
  for (int i = 0; i < 4; ++i)
    #pragma unroll
    for (int x = 0; x < 8; ++x)
      P.C[(size_t)(ma+i)*P.ldc + na + x] = acc[i][x] + bb[x];
}

// per-(b,t): logits row -> log-softmax in place + argmax word
__global__ __launch_bounds__(256) void lsm_k(float* __restrict__ out,
                                             float* __restrict__ words) {
  const int b = blockIdx.x;
  const int t = blockIdx.y;
  float* row = out + ((size_t)t*BATCH + b)*VOCAB;
  const int tid = threadIdx.x;
  float m = -INFINITY; int mi = 0;
  for (int v = tid; v < VOCAB; v += 256) {
    const float x = row[v];
    if (x > m) { m = x; mi = v; }
  }
  __shared__ float sm[256]; __shared__ int si[256];
  sm[tid] = m; si[tid] = mi;
  __syncthreads();
  for (int s2 = 128; s2; s2 >>= 1) {
    if (tid < s2) {
      const float om = sm[tid+s2]; const int oi = si[tid+s2];
      if (om > sm[tid] || (om == sm[tid] && oi < si[tid])) { sm[tid]=om; si[tid]=oi; }
    }
    __syncthreads();
  }
  const float mx = sm[0]; const int amax = si[0];
  float s = 0.f;
  for (int v = tid; v < VOCAB; v += 256) s += expf(row[v]-mx);
  __shared__ float ss[256];
  ss[tid] = s; __syncthreads();
  for (int s2=128; s2; s2>>=1) { if (tid < s2) ss[tid] += ss[tid+s2]; __syncthreads(); }
  const float lse = logf(ss[0]) + mx;
  for (int v = tid; v < VOCAB; v += 256) row[v] = row[v] - lse;
  if (tid == 0) words[(size_t)t*BATCH + b] = (float)amax;
}

__global__ __launch_bounds__(256) void init_k(const float* __restrict__ enc_h,
                                              const float* __restrict__ enc_c,
                                              const float* __restrict__ bih0,
                                              const float* __restrict__ bhh0,
                                              const float* __restrict__ bih1,
                                              const float* __restrict__ bhh1,
                                              float* h0, float* h1, float* c0,
                                              float* c1, float* zbuf,
                                              float* bsum0, float* bsum1,
                                              unsigned* cnt) {
  const int i = blockIdx.x*256 + threadIdx.x;
  if (i < BATCH*HID) {
    h0[i] = enc_h[i]; h1[i] = enc_h[BATCH*HID + i];
    c0[i] = enc_c[i]; c1[i] = enc_c[BATCH*HID + i];
    zbuf[i] = 0.f;
  }
  if (i < G4) {
    bsum0[i] = bih0[i] + bhh0[i];
    bsum1[i] = bih1[i] + bhh1[i];
  }
  if (i < 64) cnt[i] = 0u;
}

extern "C" void kernel_launch(void* const* d_in, const int* in_sizes, int n_in,
                              void* d_out, int out_size, void* d_ws, size_t ws_size,
                              hipStream_t stream) {
  const int*   tgt   = (const int*)d_in[0];
  const float* enc_h = (const float*)d_in[1];
  const float* enc_c = (const float*)d_in[2];
  const float* enc   = (const float*)d_in[3];
  const float* emb   = (const float*)d_in[4];
  const float* Wih0  = (const float*)d_in[5];
  const float* Whh0  = (const float*)d_in[6];
  const float* bih0  = (const float*)d_in[7];
  const float* bhh0  = (const float*)d_in[8];
  const float* Wih1  = (const float*)d_in[9];
  const float* Whh1  = (const float*)d_in[10];
  const float* bih1  = (const float*)d_in[11];
  const float* bhh1  = (const float*)d_in[12];
  const float* Wa    = (const float*)d_in[13];
  const float* ba    = (const float*)d_in[14];
  const float* va    = (const float*)d_in[15];
  const float* Wc    = (const float*)d_in[16];
  const float* bc    = (const float*)d_in[17];
  const float* Wo    = (const float*)d_in[18];
  const float* bo    = (const float*)d_in[19];

  float* ws    = (float*)d_ws;
  float* PreAC = ws;                                    // [2048,2048]
  float* AH    = PreAC + (size_t)2048*2048;             // [63,32,1024]
  float* Pg    = AH    + (size_t)NSTEP*BATCH*HID;       // [8,32,4096]
  float* Pq    = Pg    + (size_t)NSP*BATCH*G4;          // [8,32,2048]
  float* h0b0  = Pq    + (size_t)NSP*BATCH*2048;        // h0 ping-pong
  float* h0b1  = h0b0 + BATCH*HID;
  float* h1b0  = h0b1 + BATCH*HID;                      // h1 ping-pong
  float* h1b1  = h1b0 + BATCH*HID;
  float* c0    = h1b1 + BATCH*HID;
  float* c1v   = c0   + BATCH*HID;
  float* zbuf  = c1v  + BATCH*HID;
  float* bsum0 = zbuf + BATCH*HID;
  float* bsum1 = bsum0 + G4;
  unsigned* cnt = (unsigned*)(bsum1 + G4);              // [64]: [0:32) gates0, [32:64) gates1

  float* out   = (float*)d_out;
  float* words = out + (size_t)NSTEP*BATCH*VOCAB;

  init_k<<<dim3(128), 256, 0, stream>>>(enc_h, enc_c, bih0, bhh0, bih1, bhh1,
                                        h0b0, h1b0, c0, c1v, zbuf, bsum0, bsum1, cnt);

  { // PreAC = enc @ [Wa2; Wc2]^T + [ba; 0]  (time-invariant attention terms)
    WGP p; p.A = enc; p.W = Wa; p.W2 = Wc; p.bias = ba; p.C = PreAC; p.ldc = 2048;
    gemmL<1><<<dim3(64, 8), 256, 0, stream>>>(p);
  }

  for (int t = 0; t < NSTEP; ++t) {
    float* h0_in  = (t & 1) ? h0b1 : h0b0;
    float* h0_out = (t & 1) ? h0b0 : h0b1;
    float* h1_in  = (t & 1) ? h1b1 : h1b0;
    float* h1_out = (t & 1) ? h1b0 : h1b1;
    { // gates0 + cell0 (fused via last-block)
      GK p = {};
      p.tgt = tgt; p.emb = emb; p.t = t;
      p.segA = t ? (AH + (size_t)(t-1)*BATCH*HID) : zbuf;   // ah_prev
      p.segB = h0_in;
      p.WA = Wih0; p.WB = Whh0; p.bsum = bsum0;
      p.Pg = Pg; p.h_out = h0_out; p.c = c0; p.cnt = cnt;
      gates_k<0><<<dim3(32, NSP), 256, 0, stream>>>(p);
    }
    { // gates1 + cell1
      GK p = {};
      p.segA = h0_out; p.segB = h1_in;
      p.WA = Wih1; p.WB = Whh1; p.bsum = bsum1;
      p.Pg = Pg; p.h_out = h1_out; p.c = c1v; p.cnt = cnt + 32;
      gates_k<1><<<dim3(32, NSP), 256, 0, stream>>>(p);
    }
    { // proj partials: h1 x [Wa1; Wc1]
      PK p; p.A = h1_out; p.Wa = Wa; p.Wc = Wc; p.Pq = Pq;
      proj_k<<<dim3(64, NSP), 256, 0, stream>>>(p);
    }
    { // fused scores/softmax/context/attn_h -> AH[t]
      AK p; p.Pq = Pq; p.PreAC = PreAC; p.va = va; p.bc = bc;
      p.AHt = AH + (size_t)t*BATCH*HID;
      attn_k<<<dim3(BATCH), 256, 0, stream>>>(p);
    }
  }

  { // one batched logits GEMM over all steps: [2016 x 32000], K=1024
    WGP p; p.A = AH; p.W = Wo; p.W2 = nullptr; p.bias = bo; p.C = out; p.ldc = VOCAB;
    gemmL<0><<<dim3(NSTEP*BATCH/32, VOCAB/256), 256, 0, stream>>>(p);
  }
  lsm_k<<<dim3(BATCH, NSTEP), 256, 0, stream>>>(out, words);
}

// Round 7
// 13165.445 us; speedup vs baseline: 2.8679x; 1.3431x over previous
//
#include <hip/hip_runtime.h>
#include <math.h>

#define VOCAB 32000
#define EMBD  512
#define HID   1024
#define BATCH 32
#define SEQ   64
#define TENC  64
#define NSTEP 63
#define G4    4096
#define NSP   8            // K-splits for per-step GEMMs

__device__ __forceinline__ float4 ld4(const float* p) {
  return *reinterpret_cast<const float4*>(p);
}

// ================= per-step K-split partial GEMMs (prefetched) =================
// MODE 0: gates0 partials. A=[emb(tok)|ah_prev|h0] (K 2560, start KSTART), W=[Wih0|Whh0]
// MODE 1: gates1 partials. A=[h0|h1] K=2048, W=[Wih1|Whh1]
// MODE 2: proj partials.   A=h1 K=1024, W=[Wa1;Wc1] rows 2048
struct PP {
  const int* tgt; const float* emb;
  const float* segA; const float* segB;   // M0: ah_prev,h0 ; M1: h0,h1 ; M2: h1,-
  const float* WA; const float* WB;
  float* P; int t;
};

template<int MODE, int KSTART>
__device__ __forceinline__ float4 ldA(const PP& P, int lr, int k) {
  if (MODE == 0) {
    if (KSTART == 0 && k < EMBD) {
      const int tok = P.tgt[lr * SEQ + P.t];
      return ld4(P.emb + (size_t)tok * EMBD + k);
    }
    if (k < EMBD + HID) return ld4(P.segA + lr * HID + (k - EMBD));
    return ld4(P.segB + lr * HID + (k - EMBD - HID));
  } else if (MODE == 1) {
    if (k < HID) return ld4(P.segA + lr * HID + k);
    return ld4(P.segB + lr * HID + (k - HID));
  } else {
    return ld4(P.segA + lr * HID + k);
  }
}

template<int MODE>
__device__ __forceinline__ float4 ldW(const PP& P, int row, int k) {
  if (MODE == 0) {
    if (k < EMBD + HID) return ld4(P.WA + (size_t)row * (EMBD + HID) + k);
    return ld4(P.WB + (size_t)row * HID + (k - EMBD - HID));
  } else if (MODE == 1) {
    if (k < HID) return ld4(P.WA + (size_t)row * HID + k);
    return ld4(P.WB + (size_t)row * HID + (k - HID));
  } else {
    if (row < HID) return ld4(P.WA + (size_t)row * (2*HID) + k);
    return ld4(P.WB + (size_t)(row - HID) * (2*HID) + k);
  }
}

template<int MODE, int KSTART>
__global__ __launch_bounds__(256) void pgemm(PP P) {
  __shared__ float At[32*34];
  __shared__ float Wt[32*34];
  const int N  = (MODE == 2) ? 2048 : G4;
  const int CH = (MODE == 0) ? (2560 - KSTART)/NSP : (MODE == 1 ? 2048/NSP : 1024/NSP);
  const int nt = blockIdx.x;
  const int sp = blockIdx.y;
  const int kbeg = KSTART + sp * CH;
  const int tid = threadIdx.x;
  const int lr = tid >> 3, lc = (tid & 7) << 2;
  const int tn = tid & 15, tm = tid >> 4;
  float a00=0.f, a01=0.f, a10=0.f, a11=0.f;

  float4 av = ldA<MODE,KSTART>(P, lr, kbeg + lc);
  float4 wv = ldW<MODE>(P, nt*32 + lr, kbeg + lc);
  for (int k0 = kbeg; k0 < kbeg + CH; k0 += 32) {
    float4 avn, wvn;
    if (k0 + 32 < kbeg + CH) {
      avn = ldA<MODE,KSTART>(P, lr, k0 + 32 + lc);
      wvn = ldW<MODE>(P, nt*32 + lr, k0 + 32 + lc);
    }
    __syncthreads();
    At[(lc+0)*34+lr]=av.x; At[(lc+1)*34+lr]=av.y; At[(lc+2)*34+lr]=av.z; At[(lc+3)*34+lr]=av.w;
    Wt[(lc+0)*34+lr]=wv.x; Wt[(lc+1)*34+lr]=wv.y; Wt[(lc+2)*34+lr]=wv.z; Wt[(lc+3)*34+lr]=wv.w;
    __syncthreads();
    #pragma unroll
    for (int kk = 0; kk < 32; ++kk) {
      const float2 a = *reinterpret_cast<const float2*>(&At[kk*34 + tm*2]);
      const float2 w = *reinterpret_cast<const float2*>(&Wt[kk*34 + tn*2]);
      a00 += a.x*w.x; a01 += a.x*w.y; a10 += a.y*w.x; a11 += a.y*w.y;
    }
    av = avn; wv = wvn;
  }
  const int na = nt*32 + tn*2, ma = tm*2;
  float* dst = P.P + (size_t)sp * BATCH * N;
  dst[(size_t)(ma  )*N + na  ] = a00;
  dst[(size_t)(ma  )*N + na+1] = a01;
  dst[(size_t)(ma+1)*N + na  ] = a10;
  dst[(size_t)(ma+1)*N + na+1] = a11;
}

// reduce NSP partials (+bias, +optional Gemb row) -> LSTM cell (in-place h,c)
__global__ __launch_bounds__(256) void cellred_k(const float* __restrict__ Pg,
                                                 const float* __restrict__ bsum,
                                                 const float* __restrict__ gemb,  // or null
                                                 float* __restrict__ h,
                                                 float* __restrict__ c) {
  const int i = blockIdx.x*256 + threadIdx.x;      // b*HID + n
  const int b = i >> 10, n = i & (HID-1);
  float g4[4];
  #pragma unroll
  for (int gi = 0; gi < 4; ++gi) {
    const int col = gi*HID + n;
    float s = bsum[col];
    if (gemb) s += gemb[(size_t)b*G4 + col];
    #pragma unroll
    for (int sp = 0; sp < NSP; ++sp) s += Pg[((size_t)sp*BATCH + b)*G4 + col];
    g4[gi] = s;
  }
  const float si = 1.f/(1.f+expf(-g4[0]));
  const float sf = 1.f/(1.f+expf(-g4[1]));
  const float so = 1.f/(1.f+expf(-g4[3]));
  const float cn = sf*c[i] + si*tanhf(g4[2]);
  c[i] = cn;
  h[i] = so*tanhf(cn);
}

// ========== fused attention: q-sum, scores, softmax, context, attn_h ==========
struct AK {
  const float* Pq; const float* PreAC; const float* va; const float* bc;
  float* AHt;
};

__global__ __launch_bounds__(256) void attn_k(AK P) {
  const int b = blockIdx.x, tid = threadIdx.x;
  const int lane = tid & 63, wid = tid >> 6;
  __shared__ float QS[HID];
  __shared__ float sw[TENC];
  __shared__ float W64[TENC];
  for (int idx = tid; idx < HID; idx += 256) {
    float s = 0.f;
    #pragma unroll
    for (int sp = 0; sp < NSP; ++sp) s += P.Pq[((size_t)sp*BATCH + b)*2048 + idx];
    QS[idx] = s;
  }
  __syncthreads();
  float vreg[16];
  #pragma unroll
  for (int i2 = 0; i2 < 16; ++i2) vreg[i2] = P.va[lane + 64*i2];
  #pragma unroll
  for (int j = 0; j < 16; ++j) {
    const int te = wid*16 + j;
    const float* pr = P.PreAC + ((size_t)te*BATCH + b)*2048;
    float s = 0.f;
    #pragma unroll
    for (int i2 = 0; i2 < 16; ++i2) {
      const int idx = lane + 64*i2;
      s += vreg[i2] * tanhf(QS[idx] + pr[idx]);
    }
    #pragma unroll
    for (int off = 32; off; off >>= 1) s += __shfl_xor(s, off);
    if (lane == 0) sw[te] = s;
  }
  __syncthreads();
  if (tid < TENC) {
    const float v = sw[tid];
    float mx = v;
    #pragma unroll
    for (int off = 32; off; off >>= 1) mx = fmaxf(mx, __shfl_xor(mx, off));
    const float e = expf(v - mx);
    float sum = e;
    #pragma unroll
    for (int off = 32; off; off >>= 1) sum += __shfl_xor(sum, off);
    W64[tid] = e / sum;
  }
  __syncthreads();
  #pragma unroll
  for (int q = 0; q < 4; ++q) {
    const int hh = q*256 + tid;
    float acc = 0.f;
    #pragma unroll 8
    for (int te = 0; te < TENC; ++te)
      acc += W64[te] * P.PreAC[((size_t)te*BATCH + b)*2048 + HID + hh];
    float hc = P.bc[hh];
    #pragma unroll
    for (int sp = 0; sp < NSP; ++sp) hc += P.Pq[((size_t)sp*BATCH + b)*2048 + HID + hh];
    P.AHt[(size_t)b*HID + hh] = tanhf(acc + hc);
  }
}

// ============ wide GEMM, 32m x 256n tiles, 4x8/thread, prefetched ============
// WM 0: logits C[2016x32000] = AH*Wo^T + bo            (K=1024)
// WM 1: PreAC  C[2048x2048]  = enc*[Wa2;Wc2]^T + [ba;0] (K=1024)
// WM 2: Gemb   C[2016x4096]  = emb[tok]*Wih0[:, :512]^T (K=512, A gathered)
struct WGP {
  const float* A; const float* W; const float* W2; const float* bias;
  const int* tgt; const float* emb;
  float* C; int ldc;
};

template<int WM>
__device__ __forceinline__ float4 ldWL(const WGP& P, int r, int k) {
  if (WM == 0) return ld4(P.W + (size_t)r * 1024 + k);
  if (WM == 2) return ld4(P.W + (size_t)r * (EMBD + HID) + k);
  if (r < HID) return ld4(P.W  + (size_t)r * (2*HID) + HID + k);
  return ld4(P.W2 + (size_t)(r - HID) * (2*HID) + HID + k);
}

template<int WM>
__device__ __forceinline__ float4 ldAL(const WGP& P, int row, int k) {
  if (WM == 2) {
    const int tok = P.tgt[(row & 31) * SEQ + (row >> 5)];   // row = t*32+b
    return ld4(P.emb + (size_t)tok * EMBD + k);
  }
  return ld4(P.A + (size_t)row * 1024 + k);
}

template<int WM>
__global__ __launch_bounds__(256, 2) void gemmL(WGP P) {
  constexpr int KK = (WM == 2) ? 512 : 1024;
  __shared__ float At[32*36];
  __shared__ float Wt[32*260];
  const int tid = threadIdx.x;
  const int m0 = blockIdx.x * 32;       // m fastest: blocks sharing W-panel co-run
  const int n0 = blockIdx.y * 256;
  const int lr = tid >> 3, lc = (tid & 7) << 2;
  const int tn = tid & 31, tm = tid >> 5;
  float acc[4][8];
  #pragma unroll
  for (int i = 0; i < 4; ++i)
    #pragma unroll
    for (int x = 0; x < 8; ++x) acc[i][x] = 0.f;

  float4 av = ldAL<WM>(P, m0 + lr, lc);
  float4 wv[8];
  #pragma unroll
  for (int it = 0; it < 8; ++it) wv[it] = ldWL<WM>(P, n0 + lr + it*32, lc);

  for (int k0 = 0; k0 < KK; k0 += 32) {
    float4 avn, wvn[8];
    if (k0 + 32 < KK) {
      avn = ldAL<WM>(P, m0 + lr, k0 + 32 + lc);
      #pragma unroll
      for (int it = 0; it < 8; ++it) wvn[it] = ldWL<WM>(P, n0 + lr + it*32, k0 + 32 + lc);
    }
    __syncthreads();
    At[(lc+0)*36+lr]=av.x; At[(lc+1)*36+lr]=av.y; At[(lc+2)*36+lr]=av.z; At[(lc+3)*36+lr]=av.w;
    #pragma unroll
    for (int it = 0; it < 8; ++it) {
      const int r = lr + it*32;
      Wt[(lc+0)*260+r]=wv[it].x; Wt[(lc+1)*260+r]=wv[it].y;
      Wt[(lc+2)*260+r]=wv[it].z; Wt[(lc+3)*260+r]=wv[it].w;
    }
    __syncthreads();
    #pragma unroll
    for (int kk = 0; kk < 32; ++kk) {
      const float4 a  = *reinterpret_cast<const float4*>(&At[kk*36 + tm*4]);
      const float4 w0 = *reinterpret_cast<const float4*>(&Wt[kk*260 + tn*8]);
      const float4 w1 = *reinterpret_cast<const float4*>(&Wt[kk*260 + tn*8 + 4]);
      #pragma unroll
      for (int i = 0; i < 4; ++i) {
        const float ai = (&a.x)[i];
        acc[i][0]+=ai*w0.x; acc[i][1]+=ai*w0.y; acc[i][2]+=ai*w0.z; acc[i][3]+=ai*w0.w;
        acc[i][4]+=ai*w1.x; acc[i][5]+=ai*w1.y; acc[i][6]+=ai*w1.z; acc[i][7]+=ai*w1.w;
      }
    }
    av = avn;
    #pragma unroll
    for (int it = 0; it < 8; ++it) wv[it] = wvn[it];
  }
  const int na = n0 + tn*8, ma = m0 + tm*4;
  float bb[8];
  #pragma unroll
  for (int x = 0; x < 8; ++x) {
    if (WM == 0)      bb[x] = P.bias[na+x];
    else if (WM == 1) bb[x] = (na + x < HID) ? P.bias[na+x] : 0.f;
    else              bb[x] = 0.f;
  }
  #pragma unroll
  for (int i = 0; i < 4; ++i)
    #pragma unroll
    for (int x = 0; x < 8; ++x)
      P.C[(size_t)(ma+i)*P.ldc + na + x] = acc[i][x] + bb[x];
}

// per-(b,t): logits row -> log-softmax in place + argmax word
__global__ __launch_bounds__(256) void lsm_k(float* __restrict__ out,
                                             float* __restrict__ words) {
  const int b = blockIdx.x;
  const int t = blockIdx.y;
  float* row = out + ((size_t)t*BATCH + b)*VOCAB;
  const int tid = threadIdx.x;
  float m = -INFINITY; int mi = 0;
  for (int v = tid; v < VOCAB; v += 256) {
    const float x = row[v];
    if (x > m) { m = x; mi = v; }
  }
  __shared__ float sm[256]; __shared__ int si[256];
  sm[tid] = m; si[tid] = mi;
  __syncthreads();
  for (int s2 = 128; s2; s2 >>= 1) {
    if (tid < s2) {
      const float om = sm[tid+s2]; const int oi = si[tid+s2];
      if (om > sm[tid] || (om == sm[tid] && oi < si[tid])) { sm[tid]=om; si[tid]=oi; }
    }
    __syncthreads();
  }
  const float mx = sm[0]; const int amax = si[0];
  float s = 0.f;
  for (int v = tid; v < VOCAB; v += 256) s += expf(row[v]-mx);
  __shared__ float ss[256];
  ss[tid] = s; __syncthreads();
  for (int s2=128; s2; s2>>=1) { if (tid < s2) ss[tid] += ss[tid+s2]; __syncthreads(); }
  const float lse = logf(ss[0]) + mx;
  for (int v = tid; v < VOCAB; v += 256) row[v] = row[v] - lse;
  if (tid == 0) words[(size_t)t*BATCH + b] = (float)amax;
}

__global__ __launch_bounds__(256) void init_k(const float* __restrict__ enc_h,
                                              const float* __restrict__ enc_c,
                                              const float* __restrict__ bih0,
                                              const float* __restrict__ bhh0,
                                              const float* __restrict__ bih1,
                                              const float* __restrict__ bhh1,
                                              float* h0, float* h1, float* c0,
                                              float* c1, float* zbuf,
                                              float* bsum0, float* bsum1) {
  const int i = blockIdx.x*256 + threadIdx.x;
  if (i < BATCH*HID) {
    h0[i] = enc_h[i]; h1[i] = enc_h[BATCH*HID + i];
    c0[i] = enc_c[i]; c1[i] = enc_c[BATCH*HID + i];
    zbuf[i] = 0.f;
  }
  if (i < G4) {
    bsum0[i] = bih0[i] + bhh0[i];
    bsum1[i] = bih1[i] + bhh1[i];
  }
}

extern "C" void kernel_launch(void* const* d_in, const int* in_sizes, int n_in,
                              void* d_out, int out_size, void* d_ws, size_t ws_size,
                              hipStream_t stream) {
  const int*   tgt   = (const int*)d_in[0];
  const float* enc_h = (const float*)d_in[1];
  const float* enc_c = (const float*)d_in[2];
  const float* enc   = (const float*)d_in[3];
  const float* emb   = (const float*)d_in[4];
  const float* Wih0  = (const float*)d_in[5];
  const float* Whh0  = (const float*)d_in[6];
  const float* bih0  = (const float*)d_in[7];
  const float* bhh0  = (const float*)d_in[8];
  const float* Wih1  = (const float*)d_in[9];
  const float* Whh1  = (const float*)d_in[10];
  const float* bih1  = (const float*)d_in[11];
  const float* bhh1  = (const float*)d_in[12];
  const float* Wa    = (const float*)d_in[13];
  const float* ba    = (const float*)d_in[14];
  const float* va    = (const float*)d_in[15];
  const float* Wc    = (const float*)d_in[16];
  const float* bc    = (const float*)d_in[17];
  const float* Wo    = (const float*)d_in[18];
  const float* bo    = (const float*)d_in[19];

  float* ws    = (float*)d_ws;
  float* PreAC = ws;                                    // [2048,2048]
  float* AH    = PreAC + (size_t)2048*2048;             // [63,32,1024]
  float* Pg    = AH    + (size_t)NSTEP*BATCH*HID;       // [8,32,4096]
  float* Pq    = Pg    + (size_t)NSP*BATCH*G4;          // [8,32,2048]
  float* h0    = Pq    + (size_t)NSP*BATCH*2048;
  float* c0    = h0   + BATCH*HID;
  float* h1v   = c0   + BATCH*HID;
  float* c1v   = h1v  + BATCH*HID;
  float* zbuf  = c1v  + BATCH*HID;
  float* bsum0 = zbuf + BATCH*HID;
  float* bsum1 = bsum0 + G4;
  float* Gemb  = bsum1 + G4;                            // [63,32,4096] (optional)
  const size_t base_f = (size_t)(Gemb - ws);
  const bool hoist = ws_size >= (base_f + (size_t)NSTEP*BATCH*G4) * sizeof(float);

  float* out   = (float*)d_out;
  float* words = out + (size_t)NSTEP*BATCH*VOCAB;

  init_k<<<dim3(128), 256, 0, stream>>>(enc_h, enc_c, bih0, bhh0, bih1, bhh1,
                                        h0, h1v, c0, c1v, zbuf, bsum0, bsum1);

  { // PreAC = enc @ [Wa2; Wc2]^T + [ba; 0]
    WGP p = {}; p.A = enc; p.W = Wa; p.W2 = Wc; p.bias = ba; p.C = PreAC; p.ldc = 2048;
    gemmL<1><<<dim3(64, 8), 256, 0, stream>>>(p);
  }
  if (hoist) { // Gemb[t*32+b] = emb[tok(b,t)] @ Wih0[:, :512]^T  (teacher-forced, known upfront)
    WGP p = {}; p.W = Wih0; p.tgt = tgt; p.emb = emb; p.C = Gemb; p.ldc = G4;
    gemmL<2><<<dim3(NSTEP*BATCH/32, G4/256), 256, 0, stream>>>(p);
  }

  for (int t = 0; t < NSTEP; ++t) {
    const float* ah_prev = t ? (AH + (size_t)(t-1)*BATCH*HID) : zbuf;
    { // gates0 partials
      PP p = {}; p.tgt = tgt; p.emb = emb; p.t = t;
      p.segA = ah_prev; p.segB = h0;
      p.WA = Wih0; p.WB = Whh0; p.P = Pg;
      if (hoist) pgemm<0,EMBD><<<dim3(128, NSP), 256, 0, stream>>>(p);
      else       pgemm<0,0>   <<<dim3(128, NSP), 256, 0, stream>>>(p);
    }
    cellred_k<<<dim3(128), 256, 0, stream>>>(Pg, bsum0,
        hoist ? (Gemb + (size_t)t*BATCH*G4) : nullptr, h0, c0);
    { // gates1 partials
      PP p = {}; p.segA = h0; p.segB = h1v;
      p.WA = Wih1; p.WB = Whh1; p.P = Pg;
      pgemm<1,0><<<dim3(128, NSP), 256, 0, stream>>>(p);
    }
    cellred_k<<<dim3(128), 256, 0, stream>>>(Pg, bsum1, nullptr, h1v, c1v);
    { // proj partials: h1 x [Wa1; Wc1]
      PP p = {}; p.segA = h1v; p.WA = Wa; p.WB = Wc; p.P = Pq;
      pgemm<2,0><<<dim3(64, NSP), 256, 0, stream>>>(p);
    }
    { // fused scores/softmax/context/attn_h -> AH[t]
      AK p; p.Pq = Pq; p.PreAC = PreAC; p.va = va; p.bc = bc;
      p.AHt = AH + (size_t)t*BATCH*HID;
      attn_k<<<dim3(BATCH), 256, 0, stream>>>(p);
    }
  }

  { // batched logits: [2016 x 32000], K=1024
    WGP p = {}; p.A = AH; p.W = Wo; p.bias = bo; p.C = out; p.ldc = VOCAB;
    gemmL<0><<<dim3(NSTEP*BATCH/32, VOCAB/256), 256, 0, stream>>>(p);
  }
  lsm_k<<<dim3(BATCH, NSTEP), 256, 0, stream>>>(out, words);
}